// Round 4
// baseline (501.622 us; speedup 1.0000x reference)
//
#include <hip/hip_runtime.h>
#include <cstdint>
#include <cstddef>

// Problem constants (B=8, N=256, H=128, IN_DIM=259)
#define B_ 8
#define N_ 256
#define H_ 128

typedef float f32x4 __attribute__((ext_vector_type(4)));
typedef int i32x4 __attribute__((ext_vector_type(4)));
typedef __bf16 bf16x8 __attribute__((ext_vector_type(8)));
typedef unsigned int u32;
typedef unsigned short u16;

// ---------- helpers ----------
__device__ __forceinline__ u32 pack_bf16_pair(float lo, float hi) {
  u16 a = __builtin_bit_cast(u16, (__bf16)lo);
  u16 b = __builtin_bit_cast(u16, (__bf16)hi);
  return (u32)a | ((u32)b << 16);
}

__device__ __forceinline__ float silu_f(float x) {
  return x * __builtin_amdgcn_rcpf(1.0f + __expf(-x));
}

__device__ __forceinline__ f32x4 mfma16(i32x4 a, i32x4 b, f32x4 c) {
  return __builtin_amdgcn_mfma_f32_16x16x32_bf16(
      __builtin_bit_cast(bf16x8, a), __builtin_bit_cast(bf16x8, b), c, 0, 0, 0);
}

// ---------- precompute: R[b,n,g] = x[b,n]·W1[:, :128]ᵀ (linear layout);
// U[b,n,g] = x[b,n]·W1[:,128:256]ᵀ + b1 + W1[:,256:259]·bd, stored with in-row
// swizzle elem' = g ^ ((n&7)<<2) so main stages it linearly into LDS and reads
// bank-conflict-free f32x4 with the matching XOR. ----------
__global__ void prep_ru_kernel(const float* __restrict__ x_emb,
                               const float* __restrict__ W1,
                               const float* __restrict__ b1,
                               const float* __restrict__ bd,
                               float* __restrict__ R,
                               float* __restrict__ U) {
  __shared__ float xs[16][H_];
  const int t = threadIdx.x;          // 0..127 (= output channel g)
  const int row0 = blockIdx.x * 16;   // rows over flattened (b*N+n)
#pragma unroll
  for (int r = 0; r < 16; ++r)
    xs[r][t] = x_emb[(size_t)(row0 + r) * H_ + t];
  __syncthreads();

  const float* w1g = W1 + (size_t)t * 259;
  float accR[16], accU[16];
#pragma unroll
  for (int r = 0; r < 16; ++r) { accR[r] = 0.f; accU[r] = 0.f; }
  for (int h = 0; h < H_; ++h) {
    float wa = w1g[h];
    float wb = w1g[128 + h];
#pragma unroll
    for (int r = 0; r < 16; ++r) {
      accR[r] += xs[r][h] * wa;
      accU[r] += xs[r][h] * wb;
    }
  }
  float bias = b1[t] + bd[0] * w1g[256] + bd[1] * w1g[257] + bd[2] * w1g[258];
#pragma unroll
  for (int r = 0; r < 16; ++r) {
    int n = (row0 + r) & (N_ - 1);
    R[(size_t)(row0 + r) * H_ + t] = accR[r];
    U[(size_t)(row0 + r) * H_ + (t ^ ((n & 7) << 2))] = accU[r] + bias;
  }
}

// ---------- precompute weights (bf16, pre-swizzled for linear LDS staging):
// We = W1[:,256:259]·Wd : logical row-element kt*32+kg*8+e, 16B granule (4kt+kg)
//   stored at granule ^ (g&7).
// W2p: logical element (kt2,kg,e) = W2[g][32kt2 + 16(e>>2) + 4kg + (e&3)]
//   so the layer-2 A-frag is ONE b128 read; granule (4kt2+kg) stored ^ (g&7).
__global__ void prep_w_kernel(const float* __restrict__ W1,
                              const float* __restrict__ Wd,
                              const float* __restrict__ W2,
                              u16* __restrict__ We_b,
                              u16* __restrict__ W2_b) {
  const int idx = blockIdx.x * 256 + threadIdx.x;  // 0..16383
  const int g = idx >> 7, h = idx & 127;
  const float* w1g = W1 + (size_t)g * 259 + 256;
  float we = w1g[0] * Wd[h] + w1g[1] * Wd[128 + h] + w1g[2] * Wd[256 + h];
  int se = (h >> 3) ^ (g & 7);                       // 16B granule 0..15
  We_b[g * 128 + (se << 3) + (h & 7)] = __builtin_bit_cast(u16, (__bf16)we);

  // W2 permutation: h = 32*kt2 + 16*m + 4*kg + r  ->  slot e = 4m + r
  int kt2 = h >> 5, m = (h >> 4) & 1, kg = (h >> 2) & 3, r = h & 3;
  int gr = ((kt2 << 2) | kg) ^ (g & 7);              // swizzled 16B granule
  int e = (m << 2) | r;
  W2_b[g * 128 + (gr << 3) + e] = __builtin_bit_cast(u16, (__bf16)W2[idx]);
}

// ---------- main fused kernel ----------
// Persistent-ish: 512 blocks (b, ig), 512 thr = 8 waves = 4 i × 2 jtw.
// j-loop: 8 iterations × 32-j U-tiles; wave handles 16 j per iteration.
// LDS 80KB: [0,32K) We, [32K,64K) W2p, [64K,80K) U tile (32 rows, f32, swizzled).
// Pipeline: pe rows + U tile for jt+1 loaded to regs during jt compute (T14);
// U written to LDS between the two iteration barriers.
__launch_bounds__(512, 4)
__global__ void posupd_main(const float* __restrict__ pe,
                            const float* __restrict__ cd,
                            const float* __restrict__ pmask,
                            const float* __restrict__ b2,
                            const float* __restrict__ W3,
                            const float* __restrict__ R,
                            const float* __restrict__ U,
                            const uint4* __restrict__ Wcomb,  // We_b | W2p_b, 64KB
                            float* __restrict__ partial) {
  __shared__ uint4 ldsv[5120];  // 80 KB
  char* lds = (char*)ldsv;
  const int tid = threadIdx.x;
  const int lane = tid & 63, wv = tid >> 6;          // wv 0..7
  const int b = blockIdx.x >> 6, ig = blockIdx.x & 63;
  const int iw = wv & 3, jtw = wv >> 2;
  const int i = ig * 4 + iw;
  const int tok = lane & 15, kg = lane >> 4;
  const int jl = (jtw << 4) + tok;                   // local row in 32-row U tile
  const size_t bi = (size_t)b * N_ + i;

  // ---- prologue: stage weights (64KB) + U[0] (16KB) via regs->LDS ----
  {
    uint4 wb[8], ub[2];
#pragma unroll
    for (int c = 0; c < 8; ++c) wb[c] = Wcomb[(((wv << 3) + c) << 6) + lane];
    const uint4* Us = (const uint4*)(U + (size_t)b * N_ * H_);  // rows 0..31
#pragma unroll
    for (int c = 0; c < 2; ++c) ub[c] = Us[(((wv << 1) + c) << 6) + lane];
#pragma unroll
    for (int c = 0; c < 8; ++c)
      *reinterpret_cast<uint4*>(lds + (((wv << 3) + c) << 10) + (lane << 4)) = wb[c];
#pragma unroll
    for (int c = 0; c < 2; ++c)
      *reinterpret_cast<uint4*>(lds + 65536 + (((wv << 1) + c) << 10) + (lane << 4)) = ub[c];
  }

  const float* peBase = pe + bi * N_ * H_;
  const float* Rrow = R + bi * H_;
  const int swz = (tok & 7) << 4;

  // pe prefetch for jt=0
  f32x4 pf[8];
  {
    const float* p = peBase + (size_t)jl * H_;
#pragma unroll
    for (int kt = 0; kt < 4; ++kt) {
      pf[2 * kt]     = *reinterpret_cast<const f32x4*>(p + kt * 32 + kg * 8);
      pf[2 * kt + 1] = *reinterpret_cast<const f32x4*>(p + kt * 32 + kg * 8 + 4);
    }
  }
  __syncthreads();

  float accd0 = 0.f, accd1 = 0.f, accd2 = 0.f;

  for (int jt = 0; jt < 8; ++jt) {
    // ---- convert current pe regs -> bf16 B-frags (slot(kg,e): k = 32kt+8kg+e) ----
    i32x4 bpe[4];
#pragma unroll
    for (int kt = 0; kt < 4; ++kt) {
      f32x4 lo = pf[2 * kt], hi = pf[2 * kt + 1];
      i32x4 f;
      f.x = (int)pack_bf16_pair(lo.x, lo.y);
      f.y = (int)pack_bf16_pair(lo.z, lo.w);
      f.z = (int)pack_bf16_pair(hi.x, hi.y);
      f.w = (int)pack_bf16_pair(hi.z, hi.w);
      bpe[kt] = f;
    }

    // ---- issue next-tile loads early (U first, then pe -> counted waits keep pe in flight) ----
    uint4 ub0, ub1;
    f32x4 pfn[8];
    if (jt < 7) {
      const uint4* Us = (const uint4*)(U + ((size_t)b * N_ + (jt + 1) * 32) * H_);
      ub0 = Us[(((wv << 1) + 0) << 6) + lane];
      ub1 = Us[(((wv << 1) + 1) << 6) + lane];
      const float* p = peBase + (size_t)((jt + 1) * 32 + jl) * H_;
#pragma unroll
      for (int kt = 0; kt < 4; ++kt) {
        pfn[2 * kt]     = *reinterpret_cast<const f32x4*>(p + kt * 32 + kg * 8);
        pfn[2 * kt + 1] = *reinterpret_cast<const f32x4*>(p + kt * 32 + kg * 8 + 4);
      }
    }

    // ---- Phase B: layer-1 GEMM (A=We from LDS, b128 swizzled) ----
    f32x4 a1[8];
#pragma unroll
    for (int mt = 0; mt < 8; ++mt) { a1[mt].x = a1[mt].y = a1[mt].z = a1[mt].w = 0.f; }
#pragma unroll
    for (int kt = 0; kt < 4; ++kt) {
#pragma unroll
      for (int mt = 0; mt < 8; ++mt) {
        int off = ((16 * mt + tok) << 8) + (((kt << 6) + (kg << 4)) ^ swz);
        i32x4 afr = *reinterpret_cast<const i32x4*>(lds + off);
        a1[mt] = mfma16(afr, bpe[kt], a1[mt]);
      }
    }

    // ---- Phase B2: + R_i + U_j (LDS), SiLU, pack ----
    // C/D layout: a1[mt][r] = pre[16mt + 4kg + r][tok]
    u32 pk0[8], pk1[8];
#pragma unroll
    for (int mt = 0; mt < 8; ++mt) {
      int ch = mt * 16 + kg * 4;
      f32x4 rr = *reinterpret_cast<const f32x4*>(Rrow + ch);
      int ub = 65536 + (jl << 9) + ((ch << 2) ^ ((jl & 7) << 4));
      f32x4 uu = *reinterpret_cast<const f32x4*>(lds + ub);
      float h0 = silu_f(a1[mt].x + rr.x + uu.x);
      float h1 = silu_f(a1[mt].y + rr.y + uu.y);
      float h2 = silu_f(a1[mt].z + rr.z + uu.z);
      float h3 = silu_f(a1[mt].w + rr.w + uu.w);
      pk0[mt] = pack_bf16_pair(h0, h1);
      pk1[mt] = pack_bf16_pair(h2, h3);
    }

    // ---- Phase C: layer-2 GEMM; B-frag = lane's own pk words; A = W2p one b128 ----
    f32x4 a2[8];
#pragma unroll
    for (int mt = 0; mt < 8; ++mt) { a2[mt].x = a2[mt].y = a2[mt].z = a2[mt].w = 0.f; }
#pragma unroll
    for (int kt2 = 0; kt2 < 4; ++kt2) {
      i32x4 bfr;
      bfr.x = (int)pk0[2 * kt2];
      bfr.y = (int)pk1[2 * kt2];
      bfr.z = (int)pk0[2 * kt2 + 1];
      bfr.w = (int)pk1[2 * kt2 + 1];
#pragma unroll
      for (int mt = 0; mt < 8; ++mt) {
        int off = 32768 + ((16 * mt + tok) << 8) + (((kt2 << 6) + (kg << 4)) ^ swz);
        i32x4 afr = *reinterpret_cast<const i32x4*>(lds + off);
        a2[mt] = mfma16(afr, bfr, a2[mt]);
      }
    }

    // ---- Phase D: +b2, SiLU, partial dot with W3 ----
    float sp = 0.f;
#pragma unroll
    for (int mt = 0; mt < 8; ++mt) {
      int ch = mt * 16 + kg * 4;
      f32x4 bb = *reinterpret_cast<const f32x4*>(b2 + ch);
      f32x4 ww = *reinterpret_cast<const f32x4*>(W3 + ch);
      sp += silu_f(a2[mt].x + bb.x) * ww.x;
      sp += silu_f(a2[mt].y + bb.y) * ww.y;
      sp += silu_f(a2[mt].z + bb.z) * ww.z;
      sp += silu_f(a2[mt].w + bb.w) * ww.w;
    }

    // ---- Phase E: accumulate trans partials ----
    {
      int j = (jt << 5) + jl;
      size_t pidx = bi * N_ + j;
      float sm = sp * pmask[pidx];
      const float* c3 = cd + pidx * 3;
      accd0 += sm * c3[0];
      accd1 += sm * c3[1];
      accd2 += sm * c3[2];
    }

    // ---- iteration boundary: swap in next U tile + rotate pe prefetch ----
    __syncthreads();                       // all waves done reading U[jt]
    if (jt < 7) {
      *reinterpret_cast<uint4*>(lds + 65536 + (((wv << 1) + 0) << 10) + (lane << 4)) = ub0;
      *reinterpret_cast<uint4*>(lds + 65536 + (((wv << 1) + 1) << 10) + (lane << 4)) = ub1;
      __syncthreads();                     // U[jt+1] visible
#pragma unroll
      for (int q = 0; q < 8; ++q) pf[q] = pfn[q];
    }
  }

  // ---- wave reduction over (tok, kg) and store one partial per (b,i,jtw) ----
#pragma unroll
  for (int m = 1; m < 64; m <<= 1) {
    accd0 += __shfl_xor(accd0, m);
    accd1 += __shfl_xor(accd1, m);
    accd2 += __shfl_xor(accd2, m);
  }
  if (lane == 0) {
    float* pp = partial + ((bi << 1) + jtw) * 3;
    pp[0] = accd0; pp[1] = accd1; pp[2] = accd2;
  }
}

// ---------- deterministic reduction: out = pos + sum(2 partials) ----------
__global__ void reduce_out(const float* __restrict__ partial,
                           const float* __restrict__ pos,
                           float* __restrict__ out) {
  int t = blockIdx.x * 256 + threadIdx.x;  // 0..2047 = (b,i)
  if (t >= B_ * N_) return;
  const float* p = partial + (size_t)t * 6;
  out[t * 3 + 0] = pos[t * 3 + 0] + p[0] + p[3];
  out[t * 3 + 1] = pos[t * 3 + 1] + p[1] + p[4];
  out[t * 3 + 2] = pos[t * 3 + 2] + p[2] + p[5];
}

extern "C" void kernel_launch(void* const* d_in, const int* in_sizes, int n_in,
                              void* d_out, int out_size, void* d_ws, size_t ws_size,
                              hipStream_t stream) {
  const float* x_emb      = (const float*)d_in[0];
  const float* pair_emb   = (const float*)d_in[1];
  const float* pos        = (const float*)d_in[2];
  const float* coord_diff = (const float*)d_in[3];
  // d_in[4] node_mask: unused by the reference computation
  const float* pair_mask  = (const float*)d_in[5];
  const float* Wd         = (const float*)d_in[6];
  const float* bd         = (const float*)d_in[7];
  const float* W1         = (const float*)d_in[8];
  const float* b1         = (const float*)d_in[9];
  const float* W2         = (const float*)d_in[10];
  const float* b2         = (const float*)d_in[11];
  const float* W3         = (const float*)d_in[12];
  float* out = (float*)d_out;

  char* ws = (char*)d_ws;
  float* R       = (float*)ws;                               // 1 MB
  float* U       = (float*)(ws + (1 << 20));                 // 1 MB (swizzled rows)
  u16*   WeB     = (u16*)(ws + (2 << 20));                   // 32 KB (pre-swizzled)
  u16*   W2B     = (u16*)(ws + (2 << 20) + 32768);           // 32 KB (pre-swizzled+permuted)
  float* partial = (float*)(ws + (2 << 20) + 65536);         // 48 KB

  hipLaunchKernelGGL(prep_ru_kernel, dim3((B_ * N_) / 16), dim3(128), 0, stream,
                     x_emb, W1, b1, bd, R, U);
  hipLaunchKernelGGL(prep_w_kernel, dim3(64), dim3(256), 0, stream,
                     W1, Wd, W2, WeB, W2B);
  hipLaunchKernelGGL(posupd_main, dim3(512), dim3(512), 0, stream,
                     pair_emb, coord_diff, pair_mask, b2, W3,
                     R, U, (const uint4*)(ws + (2 << 20)), partial);
  hipLaunchKernelGGL(reduce_out, dim3(8), dim3(256), 0, stream,
                     partial, pos, out);
}